// Round 3
// baseline (809.709 us; speedup 1.0000x reference)
//
#include <hip/hip_runtime.h>

#define BATCH 32
#define NN 512
#define NODE_F 64
#define EDGE_F 16
#define MSG 80        // NODE_F + EDGE_F
#define OUTF 64
#define RD 128        // readout dim (OUT[3])
#define TGT 16
#define KMAX 8        // compact-adjacency cap; fallback to dense scan beyond
#define ROWS (BATCH*NN)  // 16384
#define RB_TOTAL 768  // readout_final_kernel grid (layers 1..3 x 256 chunks)

// ---------------------------------------------------------------------------
// K1: per (b,v) row of g: degree, compact adjacency (<=KMAX), me = sum g*e.
// Also zeroes counts[0..7] (incl. done-ticket) + accv, and zeroes h1..h3 rows
// for bucket<0 nodes (step kernels fully overwrite every bucketed row).
// one wave (64 lanes) per row; 4 waves per 256-thread block
// ---------------------------------------------------------------------------
__global__ __launch_bounds__(256) void preprocess_kernel(
    const float* __restrict__ g, const float* __restrict__ e,
    int* __restrict__ adj_idx, float* __restrict__ adj_val,
    int* __restrict__ nnzArr, int* __restrict__ bucketArr,
    float* __restrict__ me,
    float* __restrict__ h1, float* __restrict__ h2, float* __restrict__ h3,
    float* __restrict__ accv, int* __restrict__ counts)
{
  __shared__ int   s_idx[4][KMAX];
  __shared__ float s_val[4][KMAX];
  int tid  = threadIdx.x;
  int gtid = blockIdx.x * 256 + tid;
  // zero accv (4096 floats) + counts/done (8 ints); consumed by LATER dispatches
  if (gtid < BATCH*RD) accv[gtid] = 0.f;
  if (gtid < 8) counts[gtid] = 0;
  int lane = tid & 63;
  int wid  = tid >> 6;
  int row  = blockIdx.x * 4 + wid;
  const float* grow = g + (size_t)row * NN;
  float deg = 0.f;
  int cnt = 0;
  for (int it = 0; it < NN/64; ++it) {        // uniform trip count
    int w = it*64 + lane;
    float gv = grow[w];
    deg += gv;
    unsigned long long m = __ballot(gv != 0.0f);
    int before = __popcll(m & ((1ull << lane) - 1ull));
    if (gv != 0.0f) {
      int pos = cnt + before;
      if (pos < KMAX) { s_idx[wid][pos] = w; s_val[wid][pos] = gv; }
    }
    cnt += __popcll(m);
  }
  for (int off = 32; off; off >>= 1) deg += __shfl_xor(deg, off);
  __syncthreads();
  const float* erow = e + (size_t)row * NN * EDGE_F;
  if (cnt <= KMAX) {
    // parallel gather: lanes split as k = lane>>4 (neighbor), f = lane&15
    int k = lane >> 4, f = lane & 15;
    float part = 0.f;
    if (k < cnt)     part  = s_val[wid][k]   * erow[s_idx[wid][k]  *EDGE_F + f];
    if (cnt > 4) {
      int k2 = k + 4;
      if (k2 < cnt)  part += s_val[wid][k2]  * erow[s_idx[wid][k2] *EDGE_F + f];
    }
    part += __shfl_xor(part, 32);
    part += __shfl_xor(part, 16);             // every lane: sum over k for its f
    if (lane < EDGE_F) me[(size_t)row*EDGE_F + lane] = part;
  } else {                                    // general fallback: dense row
    float mef = 0.f;
    for (int w = 0; w < NN; ++w) {
      float gv = grow[w];
      if (gv != 0.f && lane < EDGE_F) mef += gv * erow[w*EDGE_F + lane];
    }
    if (lane < EDGE_F) me[(size_t)row*EDGE_F + lane] = mef;
  }
  if (lane < KMAX && lane < cnt) {
    adj_idx[row*KMAX + lane] = s_idx[wid][lane];
    adj_val[row*KMAX + lane] = s_val[wid][lane];
  }
  // all lanes have deg (post-reduction) -> bucket is wave-uniform
  int bk = -1;                                // deg not in {1,2,3,4} -> h'=0
  if      (deg == 1.0f) bk = 0;
  else if (deg == 2.0f) bk = 1;
  else if (deg == 3.0f) bk = 2;
  else if (deg == 4.0f) bk = 3;
  if (bk < 0) {                               // never-updated rows read as 0
    h1[(size_t)row*NODE_F + lane] = 0.f;
    h2[(size_t)row*NODE_F + lane] = 0.f;
    h3[(size_t)row*NODE_F + lane] = 0.f;
  }
  if (lane == 0) {
    bucketArr[row] = bk;
    nnzArr[row] = cnt;
  }
}

// ---------------------------------------------------------------------------
// Shared readout block body: 64 nodes x 128 outs GEMM (thread = 4 nodes x
// 8 outs), masked softmax, accumulate into accv[b]. Used by scatter_l0 (l=0)
// and readout_final (l=1..3). Shared arrays passed in; redm/redf overlay sht.
// ---------------------------------------------------------------------------
__device__ __forceinline__ void readout_block(
    const float* __restrict__ hs, const float* __restrict__ Wl,
    int chunk, float* __restrict__ accv,
    float* sW, float* sht, float* snmax, float* snsum, int* snflag)
{
  float* redm = sht;                          // overlay (used post-GEMM, post-sync)
  int*   redf = (int*)(sht + 64*17);
  int tid = threadIdx.x;
  { // stage W (32 KB) and h-tile (16 KB, transposed)
    const float4* W4 = (const float4*)Wl;
    float4* sW4 = (float4*)sW;
    #pragma unroll
    for (int r = 0; r < 8; ++r) sW4[tid + 256*r] = W4[tid + 256*r];
    const float4* hv4 = (const float4*)(hs + (size_t)chunk*64*NODE_F);
    #pragma unroll
    for (int r = 0; r < 4; ++r) {
      int f = tid + 256*r;                    // f < 1024: n = f>>4, chunk4 = f&15
      int n = f >> 4, c = f & 15;
      float4 v = hv4[f];
      sht[(4*c+0)*68 + n] = v.x;
      sht[(4*c+1)*68 + n] = v.y;
      sht[(4*c+2)*68 + n] = v.z;
      sht[(4*c+3)*68 + n] = v.w;
    }
  }
  __syncthreads();
  int tn = tid & 15, to = tid >> 4;           // nodes 4tn+k, outputs 8to+j
  int b = chunk >> 3;                         // 8 chunks of 64 nodes per batch
  float4 accA[4], accB[4];
  #pragma unroll
  for (int k = 0; k < 4; ++k) { accA[k] = make_float4(0,0,0,0); accB[k] = make_float4(0,0,0,0); }
  #pragma unroll 4
  for (int i = 0; i < NODE_F; ++i) {
    float4 hv = *(const float4*)&sht[i*68 + 4*tn];
    float4 w0 = *(const float4*)&sW[i*128 + 8*to];
    float4 w1 = *(const float4*)&sW[i*128 + 8*to + 4];
    float hk[4] = {hv.x, hv.y, hv.z, hv.w};
    #pragma unroll
    for (int k = 0; k < 4; ++k) {
      accA[k].x += hk[k]*w0.x; accA[k].y += hk[k]*w0.y;
      accA[k].z += hk[k]*w0.z; accA[k].w += hk[k]*w0.w;
      accB[k].x += hk[k]*w1.x; accB[k].y += hk[k]*w1.y;
      accB[k].z += hk[k]*w1.z; accB[k].w += hk[k]*w1.w;
    }
  }
  __syncthreads();                            // sht reads done -> overlay writable
  // Pass A: per-thread partial max + nonzero flag per node
  #pragma unroll
  for (int k = 0; k < 4; ++k) {
    float4 a = accA[k], bq = accB[k];
    float pm = fmaxf(fmaxf(fmaxf(a.x,a.y),fmaxf(a.z,a.w)),
                     fmaxf(fmaxf(bq.x,bq.y),fmaxf(bq.z,bq.w)));
    int nz = (a.x!=0.f)||(a.y!=0.f)||(a.z!=0.f)||(a.w!=0.f)||
             (bq.x!=0.f)||(bq.y!=0.f)||(bq.z!=0.f)||(bq.w!=0.f);
    int n = 4*tn + k;
    redm[n*17 + to] = pm;
    redf[n*17 + to] = nz;
  }
  __syncthreads();
  // Pass B: 4 threads per node reduce 16 partials
  {
    int n = tid >> 2, sub = tid & 3;
    float m = redm[n*17 + sub*4 + 0];
    m = fmaxf(m, redm[n*17 + sub*4 + 1]);
    m = fmaxf(m, redm[n*17 + sub*4 + 2]);
    m = fmaxf(m, redm[n*17 + sub*4 + 3]);
    int f = redf[n*17 + sub*4 + 0] | redf[n*17 + sub*4 + 1] |
            redf[n*17 + sub*4 + 2] | redf[n*17 + sub*4 + 3];
    m = fmaxf(m, __shfl_xor(m, 1)); m = fmaxf(m, __shfl_xor(m, 2));
    f |= __shfl_xor(f, 1); f |= __shfl_xor(f, 2);
    if (sub == 0) { snmax[n] = m; snflag[n] = f; }
  }
  __syncthreads();
  // Pass C: exp in place + partial sums
  #pragma unroll
  for (int k = 0; k < 4; ++k) {
    int n = 4*tn + k;
    float m = snmax[n];
    accA[k].x = __expf(accA[k].x - m); accA[k].y = __expf(accA[k].y - m);
    accA[k].z = __expf(accA[k].z - m); accA[k].w = __expf(accA[k].w - m);
    accB[k].x = __expf(accB[k].x - m); accB[k].y = __expf(accB[k].y - m);
    accB[k].z = __expf(accB[k].z - m); accB[k].w = __expf(accB[k].w - m);
    float ps = accA[k].x+accA[k].y+accA[k].z+accA[k].w+
               accB[k].x+accB[k].y+accB[k].z+accB[k].w;
    redm[n*17 + to] = ps;
  }
  __syncthreads();
  // Pass D: node sums
  {
    int n = tid >> 2, sub = tid & 3;
    float s = redm[n*17 + sub*4 + 0] + redm[n*17 + sub*4 + 1] +
              redm[n*17 + sub*4 + 2] + redm[n*17 + sub*4 + 3];
    s += __shfl_xor(s, 1); s += __shfl_xor(s, 2);
    if (sub == 0) snsum[n] = s;
  }
  __syncthreads();
  // Pass E: accumulate p/s over this block's nodes, reduce over tn, atomicAdd
  float4 aj0 = make_float4(0,0,0,0), aj1 = make_float4(0,0,0,0);
  #pragma unroll
  for (int k = 0; k < 4; ++k) {
    int n = 4*tn + k;
    if (snflag[n]) {
      float inv = 1.0f / snsum[n];
      aj0.x += accA[k].x*inv; aj0.y += accA[k].y*inv;
      aj0.z += accA[k].z*inv; aj0.w += accA[k].w*inv;
      aj1.x += accB[k].x*inv; aj1.y += accB[k].y*inv;
      aj1.z += accB[k].z*inv; aj1.w += accB[k].w*inv;
    }
  }
  #pragma unroll
  for (int off = 1; off < 16; off <<= 1) {
    aj0.x += __shfl_xor(aj0.x, off); aj0.y += __shfl_xor(aj0.y, off);
    aj0.z += __shfl_xor(aj0.z, off); aj0.w += __shfl_xor(aj0.w, off);
    aj1.x += __shfl_xor(aj1.x, off); aj1.y += __shfl_xor(aj1.y, off);
    aj1.z += __shfl_xor(aj1.z, off); aj1.w += __shfl_xor(aj1.w, off);
  }
  if (tn == 0) {
    float* dst = &accv[b*RD + 8*to];
    atomicAdd(dst+0, aj0.x); atomicAdd(dst+1, aj0.y);
    atomicAdd(dst+2, aj0.z); atomicAdd(dst+3, aj0.w);
    atomicAdd(dst+4, aj1.x); atomicAdd(dst+5, aj1.y);
    atomicAdd(dst+6, aj1.z); atomicAdd(dst+7, aj1.w);
  }
}

// ---------------------------------------------------------------------------
// K2: blocks 0..63: wave-aggregated bucket scatter. blocks 64..319: readout
// layer 0 (h_in @ W0) on otherwise-idle CUs (scatter alone uses 64/256 CUs).
// ---------------------------------------------------------------------------
__global__ __launch_bounds__(256) void scatter_l0_kernel(
    const int* __restrict__ bucketArr,
    int* __restrict__ counts, int* __restrict__ perm,
    const float* __restrict__ h_in, const float* __restrict__ W0,
    float* __restrict__ accv)
{
  __shared__ float sW[NODE_F*RD];             // 32 KB
  __shared__ float sht[NODE_F*68];            // 17.4 KB
  __shared__ float snmax[64], snsum[64];
  __shared__ int   snflag[64];
  if (blockIdx.x < 64) {
    int i = blockIdx.x * blockDim.x + threadIdx.x;
    int lane = threadIdx.x & 63;
    int bk = bucketArr[i];
    #pragma unroll
    for (int d = 0; d < 4; ++d) {
      unsigned long long m = __ballot(bk == d);
      if (m == 0ull) continue;                // wave-uniform
      int leader = __ffsll((long long)m) - 1;
      int tot    = __popcll(m);
      int base = 0;
      if (lane == leader) base = atomicAdd(&counts[d], tot);
      base = __shfl(base, leader);
      if (bk == d) {
        int before = __popcll(m & ((1ull << lane) - 1ull));
        perm[d*ROWS + base + before] = i;     // coalesced segment per wave
      }
    }
  } else {
    readout_block(h_in, W0, blockIdx.x - 64, accv, sW, sht, snmax, snsum, snflag);
  }
}

// ---------------------------------------------------------------------------
// K3 (x3): register-tiled GEMM: 64 same-bucket nodes/block, 256 threads,
// thread computes 4 nodes x 4 outputs. msg staged TRANSPOSED [i][n] so node
// reads are ds_read_b128; H staged in LDS (20.5 KB, read as b128 broadcast).
// ---------------------------------------------------------------------------
__global__ __launch_bounds__(256) void step_kernel(
    const float* __restrict__ h_prev, float* __restrict__ h_out,
    const float* __restrict__ Ht,
    const int* __restrict__ perm, const int* __restrict__ counts,
    const int* __restrict__ nnzArr, const int* __restrict__ adj_idx,
    const float* __restrict__ adj_val, const float* __restrict__ me,
    const float* __restrict__ g)
{
  int d = blockIdx.x >> 8;                    // 256 chunks per bucket
  int chunk = blockIdx.x & 255;
  int cnt = counts[d];
  int base = chunk * 64;
  if (base >= cnt) return;                    // uniform early-exit
  __shared__ float smt[MSG][68];              // transposed msg [i][n]
  __shared__ float sH[MSG*OUTF];              // 80x64 = 20.5 KB
  __shared__ int   srow[64];
  int tid = threadIdx.x;
  int lane = tid & 63, wid = tid >> 6;
  { // stage H (L2-resident, 20.5 KB)
    const float4* H4 = (const float4*)(Ht + (size_t)d*MSG*OUTF);
    float4* s4 = (float4*)sH;
    for (int f = tid; f < MSG*OUTF/4; f += 256) s4[f] = H4[f];
  }
  // gather: wave wid handles nodes wid*16..+15, feature = lane
  #pragma unroll 2
  for (int t = 0; t < 16; ++t) {
    int nl = wid*16 + t;
    int gi = base + nl;
    float mh = 0.f;
    int row = -1;
    if (gi < cnt) {
      row = perm[d*ROWS + gi];
      int bb = row >> 9;
      int nnz = nnzArr[row];
      if (nnz <= KMAX) {                      // wave-uniform branch
        int4   ai = *(const int4*)  &adj_idx[row*KMAX];
        float4 av = *(const float4*)&adj_val[row*KMAX];
        const float* hb = h_prev + (size_t)bb*NN*NODE_F + lane;
        if (nnz > 0) mh += av.x * hb[(size_t)ai.x*NODE_F];
        if (nnz > 1) mh += av.y * hb[(size_t)ai.y*NODE_F];
        if (nnz > 2) mh += av.z * hb[(size_t)ai.z*NODE_F];
        if (nnz > 3) mh += av.w * hb[(size_t)ai.w*NODE_F];
        if (nnz > 4) {
          int4   ai2 = *(const int4*)  &adj_idx[row*KMAX + 4];
          float4 av2 = *(const float4*)&adj_val[row*KMAX + 4];
          mh += av2.x * hb[(size_t)ai2.x*NODE_F];
          if (nnz > 5) mh += av2.y * hb[(size_t)ai2.y*NODE_F];
          if (nnz > 6) mh += av2.z * hb[(size_t)ai2.z*NODE_F];
          if (nnz > 7) mh += av2.w * hb[(size_t)ai2.w*NODE_F];
        }
      } else {                                // general fallback
        const float* grow = g + (size_t)row * NN;
        for (int w = 0; w < NN; ++w) {
          float gv = grow[w];
          if (gv != 0.f) mh += gv * h_prev[((size_t)(bb*NN + w))*NODE_F + lane];
        }
      }
    }
    smt[lane][nl] = mh;
    if (lane < EDGE_F) smt[NODE_F + lane][nl] = (row >= 0) ? me[(size_t)row*EDGE_F + lane] : 0.f;
    if (lane == 0) srow[nl] = row;
  }
  __syncthreads();
  int tn = tid & 15, to = tid >> 4;           // nodes 4tn+k, outputs 4to+j
  float4 acc[4];
  acc[0] = acc[1] = acc[2] = acc[3] = make_float4(0.f,0.f,0.f,0.f);
  #pragma unroll 8
  for (int i = 0; i < MSG; ++i) {
    float4 hv = *(const float4*)&smt[i][4*tn];
    float4 wv = *(const float4*)&sH[i*OUTF + 4*to];
    float hk[4] = {hv.x, hv.y, hv.z, hv.w};
    #pragma unroll
    for (int k = 0; k < 4; ++k) {
      acc[k].x += hk[k]*wv.x; acc[k].y += hk[k]*wv.y;
      acc[k].z += hk[k]*wv.z; acc[k].w += hk[k]*wv.w;
    }
  }
  #pragma unroll
  for (int k = 0; k < 4; ++k) {
    int r = srow[4*tn + k];
    if (r >= 0) *(float4*)&h_out[(size_t)r*OUTF + 4*to] = acc[k];
  }
}

// ---------------------------------------------------------------------------
// K4: readout layers 1..3 (768 blocks) + last-block final softmax.
// Ticket pattern: after accv atomics, threadfence+sync, thread0 atomicAdd on
// done; the block seeing RB_TOTAL-1 stages accv via agent-scope atomic loads
// (L1-bypassing) and computes out = softmax(accv @ Wf + bf).
// ---------------------------------------------------------------------------
__global__ __launch_bounds__(256) void readout_final_kernel(
    const float* __restrict__ h1, const float* __restrict__ h2,
    const float* __restrict__ h3,
    const float* __restrict__ W1, const float* __restrict__ W2,
    const float* __restrict__ W3,
    float* __restrict__ accv, int* __restrict__ done,
    const float* __restrict__ Wf, const float* __restrict__ bf,
    float* __restrict__ out)
{
  __shared__ float sW[NODE_F*RD];             // 32 KB (reused for accv staging)
  __shared__ float sht[NODE_F*68];            // 17.4 KB
  __shared__ float snmax[64], snsum[64];
  __shared__ int   snflag[64];
  __shared__ int   s_last;
  int l = blockIdx.x >> 8;                    // 0..2 -> layers 1..3
  int chunk = blockIdx.x & 255;
  const float* hs = (l==0)?h1:(l==1)?h2:h3;
  const float* Wl = (l==0)?W1:(l==1)?W2:W3;
  readout_block(hs, Wl, chunk, accv, sW, sht, snmax, snsum, snflag);
  int tid = threadIdx.x;
  __threadfence();                            // order this block's accv atomics
  __syncthreads();
  if (tid == 0) s_last = (atomicAdd(done, 1) == RB_TOTAL - 1) ? 1 : 0;
  __syncthreads();
  if (s_last) {
    __threadfence();                          // acquire side
    // stage accv (32x128 floats) via agent-scope loads (bypass stale L1)
    float* sacc = sW;
    #pragma unroll
    for (int r = 0; r < 16; ++r) {
      int j = r*256 + tid;
      sacc[j] = __hip_atomic_load(&accv[j], __ATOMIC_RELAXED, __HIP_MEMORY_SCOPE_AGENT);
    }
    __syncthreads();
    #pragma unroll
    for (int rep = 0; rep < 2; ++rep) {
      int idx = rep*256 + tid;
      int b = idx >> 4, tg = idx & 15;        // 16 consecutive lanes share b
      float v = bf[tg];
      #pragma unroll 8
      for (int i = 0; i < RD; ++i) v += sacc[b*RD + i] * Wf[i*TGT + tg];
      float mx = v;
      for (int off = 8; off; off >>= 1) mx = fmaxf(mx, __shfl_xor(mx, off, 16));
      float e2 = __expf(v - mx);
      float s = e2;
      for (int off = 8; off; off >>= 1) s += __shfl_xor(s, off, 16);
      out[b*TGT + tg] = e2 / s;
    }
  }
}

extern "C" void kernel_launch(void* const* d_in, const int* in_sizes, int n_in,
                              void* d_out, int out_size, void* d_ws, size_t ws_size,
                              hipStream_t stream)
{
  const float* g    = (const float*)d_in[0];
  const float* h_in = (const float*)d_in[1];
  const float* e    = (const float*)d_in[2];
  const float* H0   = (const float*)d_in[3];
  const float* H1   = (const float*)d_in[4];
  const float* H2   = (const float*)d_in[5];
  const float* W0   = (const float*)d_in[6];
  const float* W1   = (const float*)d_in[7];
  const float* W2   = (const float*)d_in[8];
  const float* W3   = (const float*)d_in[9];
  const float* Wf   = (const float*)d_in[10];
  const float* bf   = (const float*)d_in[11];
  float* out = (float*)d_out;

  char* base = (char*)d_ws;
  size_t off = 0;
  auto alloc = [&](size_t bytes) -> void* {
    void* p = base + off;
    off = (off + bytes + 255) & ~(size_t)255;
    return p;
  };
  int*   adj_idx   = (int*)  alloc((size_t)ROWS*KMAX*sizeof(int));
  float* adj_val   = (float*)alloc((size_t)ROWS*KMAX*sizeof(float));
  int*   nnzArr    = (int*)  alloc((size_t)ROWS*sizeof(int));
  int*   bucketArr = (int*)  alloc((size_t)ROWS*sizeof(int));
  float* me        = (float*)alloc((size_t)ROWS*EDGE_F*sizeof(float));
  int*   perm      = (int*)  alloc((size_t)4*ROWS*sizeof(int));
  int*   counts    = (int*)  alloc(8*sizeof(int) + (size_t)BATCH*RD*sizeof(float));
  int*   done      = counts + 4;              // ticket for readout_final
  float* accv      = (float*)(counts + 8);
  float* h1        = (float*)alloc((size_t)ROWS*NODE_F*sizeof(float)*3);
  float* h2 = h1 + (size_t)ROWS*NODE_F;
  float* h3 = h2 + (size_t)ROWS*NODE_F;

  // 6 dispatches, no memsets: preprocess zeroes counts/done/accv + bucket<0
  // h-rows; scatter dispatch also runs readout layer 0 on idle CUs; readout
  // (layers 1-3) fuses the final softmax via last-block ticket.
  preprocess_kernel<<<ROWS/4, 256, 0, stream>>>(g, e, adj_idx, adj_val, nnzArr, bucketArr, me,
                                                h1, h2, h3, accv, counts);
  scatter_l0_kernel<<<64 + 256, 256, 0, stream>>>(bucketArr, counts, perm, h_in, W0, accv);
  step_kernel<<<4*256, 256, 0, stream>>>(h_in, h1, H0, perm, counts, nnzArr, adj_idx, adj_val, me, g);
  step_kernel<<<4*256, 256, 0, stream>>>(h1,   h2, H1, perm, counts, nnzArr, adj_idx, adj_val, me, g);
  step_kernel<<<4*256, 256, 0, stream>>>(h2,   h3, H2, perm, counts, nnzArr, adj_idx, adj_val, me, g);
  readout_final_kernel<<<RB_TOTAL, 256, 0, stream>>>(h1, h2, h3, W1, W2, W3,
                                                     accv, done, Wf, bf, out);
}

// Round 4
// 758.961 us; speedup vs baseline: 1.0669x; 1.0669x over previous
//
#include <hip/hip_runtime.h>

#define BATCH 32
#define NN 512
#define NODE_F 64
#define EDGE_F 16
#define MSG 80        // NODE_F + EDGE_F
#define OUTF 64
#define RD 128        // readout dim (OUT[3])
#define TGT 16
#define KMAX 8        // compact-adjacency cap; fallback to dense scan beyond
#define ROWS (BATCH*NN)  // 16384
#define STEP_BLKS 1024   // 4 buckets x 256 chunks
#define RO_BLKS 256      // readout chunks per layer

// ---------------------------------------------------------------------------
// K1: per (b,v) row of g: degree, compact adjacency (<=KMAX), me = sum g*e.
// Also zeroes counts+accv and h1..h3 rows for bucket<0 nodes.
// one wave (64 lanes) per row; 4 waves per 256-thread block
// ---------------------------------------------------------------------------
__global__ __launch_bounds__(256) void preprocess_kernel(
    const float* __restrict__ g, const float* __restrict__ e,
    int* __restrict__ adj_idx, float* __restrict__ adj_val,
    int* __restrict__ nnzArr, int* __restrict__ bucketArr,
    float* __restrict__ me,
    float* __restrict__ h1, float* __restrict__ h2, float* __restrict__ h3,
    float* __restrict__ accv, int* __restrict__ counts)
{
  __shared__ int   s_idx[4][KMAX];
  __shared__ float s_val[4][KMAX];
  int tid  = threadIdx.x;
  int gtid = blockIdx.x * 256 + tid;
  // zero accv (4096 floats) + counts (8 ints); consumed by LATER dispatches
  if (gtid < BATCH*RD) accv[gtid] = 0.f;
  if (gtid < 8) counts[gtid] = 0;
  int lane = tid & 63;
  int wid  = tid >> 6;
  int row  = blockIdx.x * 4 + wid;
  const float* grow = g + (size_t)row * NN;
  float deg = 0.f;
  int cnt = 0;
  for (int it = 0; it < NN/64; ++it) {        // uniform trip count
    int w = it*64 + lane;
    float gv = grow[w];
    deg += gv;
    unsigned long long m = __ballot(gv != 0.0f);
    int before = __popcll(m & ((1ull << lane) - 1ull));
    if (gv != 0.0f) {
      int pos = cnt + before;
      if (pos < KMAX) { s_idx[wid][pos] = w; s_val[wid][pos] = gv; }
    }
    cnt += __popcll(m);
  }
  for (int off = 32; off; off >>= 1) deg += __shfl_xor(deg, off);
  __syncthreads();
  const float* erow = e + (size_t)row * NN * EDGE_F;
  if (cnt <= KMAX) {
    // parallel gather: lanes split as k = lane>>4 (neighbor), f = lane&15
    int k = lane >> 4, f = lane & 15;
    float part = 0.f;
    if (k < cnt)     part  = s_val[wid][k]   * erow[s_idx[wid][k]  *EDGE_F + f];
    if (cnt > 4) {
      int k2 = k + 4;
      if (k2 < cnt)  part += s_val[wid][k2]  * erow[s_idx[wid][k2] *EDGE_F + f];
    }
    part += __shfl_xor(part, 32);
    part += __shfl_xor(part, 16);             // every lane: sum over k for its f
    if (lane < EDGE_F) me[(size_t)row*EDGE_F + lane] = part;
  } else {                                    // general fallback: dense row
    float mef = 0.f;
    for (int w = 0; w < NN; ++w) {
      float gv = grow[w];
      if (gv != 0.f && lane < EDGE_F) mef += gv * erow[w*EDGE_F + lane];
    }
    if (lane < EDGE_F) me[(size_t)row*EDGE_F + lane] = mef;
  }
  if (lane < KMAX && lane < cnt) {
    adj_idx[row*KMAX + lane] = s_idx[wid][lane];
    adj_val[row*KMAX + lane] = s_val[wid][lane];
  }
  // all lanes have deg (post-reduction) -> bucket is wave-uniform
  int bk = -1;                                // deg not in {1,2,3,4} -> h'=0
  if      (deg == 1.0f) bk = 0;
  else if (deg == 2.0f) bk = 1;
  else if (deg == 3.0f) bk = 2;
  else if (deg == 4.0f) bk = 3;
  if (bk < 0) {                               // never-updated rows read as 0
    h1[(size_t)row*NODE_F + lane] = 0.f;
    h2[(size_t)row*NODE_F + lane] = 0.f;
    h3[(size_t)row*NODE_F + lane] = 0.f;
  }
  if (lane == 0) {
    bucketArr[row] = bk;
    nnzArr[row] = cnt;
  }
}

// ---------------------------------------------------------------------------
// K2: bucket-sort node ids. WAVE-AGGREGATED: one atomicAdd per (wave,bucket).
// ---------------------------------------------------------------------------
__global__ __launch_bounds__(256) void scatter_kernel(
    const int* __restrict__ bucketArr,
    int* __restrict__ counts, int* __restrict__ perm)
{
  int i = blockIdx.x * blockDim.x + threadIdx.x;
  int lane = threadIdx.x & 63;
  int bk = bucketArr[i];                      // grid == ROWS exactly
  #pragma unroll
  for (int d = 0; d < 4; ++d) {
    unsigned long long m = __ballot(bk == d);
    if (m == 0ull) continue;                  // wave-uniform
    int leader = __ffsll((long long)m) - 1;
    int tot    = __popcll(m);
    int base = 0;
    if (lane == leader) base = atomicAdd(&counts[d], tot);
    base = __shfl(base, leader);
    if (bk == d) {
      int before = __popcll(m & ((1ull << lane) - 1ull));
      perm[d*ROWS + base + before] = i;       // coalesced segment per wave
    }
  }
}

// ---------------------------------------------------------------------------
// LDS union: step needs 42.5 KB, readout 51 KB -> 51 KB, 3 blocks/CU either way
// ---------------------------------------------------------------------------
union StepRO {
  struct { float smt[MSG][68]; float sH[MSG*OUTF]; int srow[64]; } s;
  struct { float sW[NODE_F*RD]; float sht[NODE_F*68];
           float snmax[64]; float snsum[64]; int snflag[64]; } r;
};

// ---------------------------------------------------------------------------
// Readout block body: 64 nodes x 128 outs GEMM (thread = 4 nodes x 8 outs),
// masked softmax, accumulate into accv[b]. redm/redf overlay sht (post-sync).
// ---------------------------------------------------------------------------
__device__ __forceinline__ void readout_block(
    const float* __restrict__ hs, const float* __restrict__ Wl,
    int chunk, float* __restrict__ accv,
    float* sW, float* sht, float* snmax, float* snsum, int* snflag)
{
  float* redm = sht;                          // overlay (used post-GEMM, post-sync)
  int*   redf = (int*)(sht + 64*17);
  int tid = threadIdx.x;
  { // stage W (32 KB) and h-tile (16 KB, transposed)
    const float4* W4 = (const float4*)Wl;
    float4* sW4 = (float4*)sW;
    #pragma unroll
    for (int r = 0; r < 8; ++r) sW4[tid + 256*r] = W4[tid + 256*r];
    const float4* hv4 = (const float4*)(hs + (size_t)chunk*64*NODE_F);
    #pragma unroll
    for (int r = 0; r < 4; ++r) {
      int f = tid + 256*r;                    // f < 1024: n = f>>4, chunk4 = f&15
      int n = f >> 4, c = f & 15;
      float4 v = hv4[f];
      sht[(4*c+0)*68 + n] = v.x;
      sht[(4*c+1)*68 + n] = v.y;
      sht[(4*c+2)*68 + n] = v.z;
      sht[(4*c+3)*68 + n] = v.w;
    }
  }
  __syncthreads();
  int tn = tid & 15, to = tid >> 4;           // nodes 4tn+k, outputs 8to+j
  int b = chunk >> 3;                         // 8 chunks of 64 nodes per batch
  float4 accA[4], accB[4];
  #pragma unroll
  for (int k = 0; k < 4; ++k) { accA[k] = make_float4(0,0,0,0); accB[k] = make_float4(0,0,0,0); }
  #pragma unroll 4
  for (int i = 0; i < NODE_F; ++i) {
    float4 hv = *(const float4*)&sht[i*68 + 4*tn];
    float4 w0 = *(const float4*)&sW[i*128 + 8*to];
    float4 w1 = *(const float4*)&sW[i*128 + 8*to + 4];
    float hk[4] = {hv.x, hv.y, hv.z, hv.w};
    #pragma unroll
    for (int k = 0; k < 4; ++k) {
      accA[k].x += hk[k]*w0.x; accA[k].y += hk[k]*w0.y;
      accA[k].z += hk[k]*w0.z; accA[k].w += hk[k]*w0.w;
      accB[k].x += hk[k]*w1.x; accB[k].y += hk[k]*w1.y;
      accB[k].z += hk[k]*w1.z; accB[k].w += hk[k]*w1.w;
    }
  }
  __syncthreads();                            // sht reads done -> overlay writable
  // Pass A: per-thread partial max + nonzero flag per node
  #pragma unroll
  for (int k = 0; k < 4; ++k) {
    float4 a = accA[k], bq = accB[k];
    float pm = fmaxf(fmaxf(fmaxf(a.x,a.y),fmaxf(a.z,a.w)),
                     fmaxf(fmaxf(bq.x,bq.y),fmaxf(bq.z,bq.w)));
    int nz = (a.x!=0.f)||(a.y!=0.f)||(a.z!=0.f)||(a.w!=0.f)||
             (bq.x!=0.f)||(bq.y!=0.f)||(bq.z!=0.f)||(bq.w!=0.f);
    int n = 4*tn + k;
    redm[n*17 + to] = pm;
    redf[n*17 + to] = nz;
  }
  __syncthreads();
  // Pass B: 4 threads per node reduce 16 partials
  {
    int n = tid >> 2, sub = tid & 3;
    float m = redm[n*17 + sub*4 + 0];
    m = fmaxf(m, redm[n*17 + sub*4 + 1]);
    m = fmaxf(m, redm[n*17 + sub*4 + 2]);
    m = fmaxf(m, redm[n*17 + sub*4 + 3]);
    int f = redf[n*17 + sub*4 + 0] | redf[n*17 + sub*4 + 1] |
            redf[n*17 + sub*4 + 2] | redf[n*17 + sub*4 + 3];
    m = fmaxf(m, __shfl_xor(m, 1)); m = fmaxf(m, __shfl_xor(m, 2));
    f |= __shfl_xor(f, 1); f |= __shfl_xor(f, 2);
    if (sub == 0) { snmax[n] = m; snflag[n] = f; }
  }
  __syncthreads();
  // Pass C: exp in place + partial sums
  #pragma unroll
  for (int k = 0; k < 4; ++k) {
    int n = 4*tn + k;
    float m = snmax[n];
    accA[k].x = __expf(accA[k].x - m); accA[k].y = __expf(accA[k].y - m);
    accA[k].z = __expf(accA[k].z - m); accA[k].w = __expf(accA[k].w - m);
    accB[k].x = __expf(accB[k].x - m); accB[k].y = __expf(accB[k].y - m);
    accB[k].z = __expf(accB[k].z - m); accB[k].w = __expf(accB[k].w - m);
    float ps = accA[k].x+accA[k].y+accA[k].z+accA[k].w+
               accB[k].x+accB[k].y+accB[k].z+accB[k].w;
    redm[n*17 + to] = ps;
  }
  __syncthreads();
  // Pass D: node sums
  {
    int n = tid >> 2, sub = tid & 3;
    float s = redm[n*17 + sub*4 + 0] + redm[n*17 + sub*4 + 1] +
              redm[n*17 + sub*4 + 2] + redm[n*17 + sub*4 + 3];
    s += __shfl_xor(s, 1); s += __shfl_xor(s, 2);
    if (sub == 0) snsum[n] = s;
  }
  __syncthreads();
  // Pass E: accumulate p/s over this block's nodes, reduce over tn, atomicAdd
  float4 aj0 = make_float4(0,0,0,0), aj1 = make_float4(0,0,0,0);
  #pragma unroll
  for (int k = 0; k < 4; ++k) {
    int n = 4*tn + k;
    if (snflag[n]) {
      float inv = 1.0f / snsum[n];
      aj0.x += accA[k].x*inv; aj0.y += accA[k].y*inv;
      aj0.z += accA[k].z*inv; aj0.w += accA[k].w*inv;
      aj1.x += accB[k].x*inv; aj1.y += accB[k].y*inv;
      aj1.z += accB[k].z*inv; aj1.w += accB[k].w*inv;
    }
  }
  #pragma unroll
  for (int off = 1; off < 16; off <<= 1) {
    aj0.x += __shfl_xor(aj0.x, off); aj0.y += __shfl_xor(aj0.y, off);
    aj0.z += __shfl_xor(aj0.z, off); aj0.w += __shfl_xor(aj0.w, off);
    aj1.x += __shfl_xor(aj1.x, off); aj1.y += __shfl_xor(aj1.y, off);
    aj1.z += __shfl_xor(aj1.z, off); aj1.w += __shfl_xor(aj1.w, off);
  }
  if (tn == 0) {
    float* dst = &accv[b*RD + 8*to];
    atomicAdd(dst+0, aj0.x); atomicAdd(dst+1, aj0.y);
    atomicAdd(dst+2, aj0.z); atomicAdd(dst+3, aj0.w);
    atomicAdd(dst+4, aj1.x); atomicAdd(dst+5, aj1.y);
    atomicAdd(dst+6, aj1.z); atomicAdd(dst+7, aj1.w);
  }
}

// ---------------------------------------------------------------------------
// K3 (x3): blocks 0..1023: step GEMM (64 same-bucket nodes/block, thread =
// 4 nodes x 4 outputs; ~768 blocks early-exit). blocks 1024..1279: readout
// layer for h_ro/W_ro (data ready since the PREVIOUS dispatch) on the CUs
// the early-exit blocks leave idle. No fences — kernel-boundary ordering only.
// ---------------------------------------------------------------------------
__global__ __launch_bounds__(256) void step_ro_kernel(
    const float* __restrict__ h_prev, float* __restrict__ h_out,
    const float* __restrict__ Ht,
    const int* __restrict__ perm, const int* __restrict__ counts,
    const int* __restrict__ nnzArr, const int* __restrict__ adj_idx,
    const float* __restrict__ adj_val, const float* __restrict__ me,
    const float* __restrict__ g,
    const float* __restrict__ h_ro, const float* __restrict__ W_ro,
    float* __restrict__ accv)
{
  __shared__ StepRO u;
  int tid = threadIdx.x;
  if (blockIdx.x >= STEP_BLKS) {              // block-uniform branch
    readout_block(h_ro, W_ro, blockIdx.x - STEP_BLKS, accv,
                  u.r.sW, u.r.sht, u.r.snmax, u.r.snsum, u.r.snflag);
    return;
  }
  int d = blockIdx.x >> 8;                    // 256 chunks per bucket
  int chunk = blockIdx.x & 255;
  int cnt = counts[d];
  int base = chunk * 64;
  if (base >= cnt) return;                    // uniform early-exit
  int lane = tid & 63, wid = tid >> 6;
  { // stage H (L2-resident, 20.5 KB)
    const float4* H4 = (const float4*)(Ht + (size_t)d*MSG*OUTF);
    float4* s4 = (float4*)u.s.sH;
    for (int f = tid; f < MSG*OUTF/4; f += 256) s4[f] = H4[f];
  }
  // gather: wave wid handles nodes wid*16..+15, feature = lane
  #pragma unroll 2
  for (int t = 0; t < 16; ++t) {
    int nl = wid*16 + t;
    int gi = base + nl;
    float mh = 0.f;
    int row = -1;
    if (gi < cnt) {
      row = perm[d*ROWS + gi];
      int bb = row >> 9;
      int nnz = nnzArr[row];
      if (nnz <= KMAX) {                      // wave-uniform branch
        int4   ai = *(const int4*)  &adj_idx[row*KMAX];
        float4 av = *(const float4*)&adj_val[row*KMAX];
        const float* hb = h_prev + (size_t)bb*NN*NODE_F + lane;
        if (nnz > 0) mh += av.x * hb[(size_t)ai.x*NODE_F];
        if (nnz > 1) mh += av.y * hb[(size_t)ai.y*NODE_F];
        if (nnz > 2) mh += av.z * hb[(size_t)ai.z*NODE_F];
        if (nnz > 3) mh += av.w * hb[(size_t)ai.w*NODE_F];
        if (nnz > 4) {
          int4   ai2 = *(const int4*)  &adj_idx[row*KMAX + 4];
          float4 av2 = *(const float4*)&adj_val[row*KMAX + 4];
          mh += av2.x * hb[(size_t)ai2.x*NODE_F];
          if (nnz > 5) mh += av2.y * hb[(size_t)ai2.y*NODE_F];
          if (nnz > 6) mh += av2.z * hb[(size_t)ai2.z*NODE_F];
          if (nnz > 7) mh += av2.w * hb[(size_t)ai2.w*NODE_F];
        }
      } else {                                // general fallback
        const float* grow = g + (size_t)row * NN;
        for (int w = 0; w < NN; ++w) {
          float gv = grow[w];
          if (gv != 0.f) mh += gv * h_prev[((size_t)(bb*NN + w))*NODE_F + lane];
        }
      }
    }
    u.s.smt[lane][nl] = mh;
    if (lane < EDGE_F) u.s.smt[NODE_F + lane][nl] = (row >= 0) ? me[(size_t)row*EDGE_F + lane] : 0.f;
    if (lane == 0) u.s.srow[nl] = row;
  }
  __syncthreads();
  int tn = tid & 15, to = tid >> 4;           // nodes 4tn+k, outputs 4to+j
  float4 acc[4];
  acc[0] = acc[1] = acc[2] = acc[3] = make_float4(0.f,0.f,0.f,0.f);
  #pragma unroll 8
  for (int i = 0; i < MSG; ++i) {
    float4 hv = *(const float4*)&u.s.smt[i][4*tn];
    float4 wv = *(const float4*)&u.s.sH[i*OUTF + 4*to];
    float hk[4] = {hv.x, hv.y, hv.z, hv.w};
    #pragma unroll
    for (int k = 0; k < 4; ++k) {
      acc[k].x += hk[k]*wv.x; acc[k].y += hk[k]*wv.y;
      acc[k].z += hk[k]*wv.z; acc[k].w += hk[k]*wv.w;
    }
  }
  #pragma unroll
  for (int k = 0; k < 4; ++k) {
    int r = u.s.srow[4*tn + k];
    if (r >= 0) *(float4*)&h_out[(size_t)r*OUTF + 4*to] = acc[k];
  }
}

// ---------------------------------------------------------------------------
// K4: readout layer 3 only (256 blocks; layers 0-2 rode inside step dispatches)
// ---------------------------------------------------------------------------
__global__ __launch_bounds__(256) void readout_l3_kernel(
    const float* __restrict__ h3, const float* __restrict__ W3,
    float* __restrict__ accv)
{
  __shared__ StepRO u;
  readout_block(h3, W3, blockIdx.x, accv,
                u.r.sW, u.r.sht, u.r.snmax, u.r.snsum, u.r.snflag);
}

// ---------------------------------------------------------------------------
// K5: out[b] = softmax(acc[b] @ W_final + b_final); one block per batch
// ---------------------------------------------------------------------------
__global__ __launch_bounds__(256) void final_kernel(
    const float* __restrict__ accv, const float* __restrict__ Wf,
    const float* __restrict__ bf, float* __restrict__ out)
{
  int b = blockIdx.x;
  int tid = threadIdx.x;
  int tg = tid & 15, part = tid >> 4;         // 16 parts x 8 i's each
  float p = 0.f;
  #pragma unroll
  for (int q = 0; q < 8; ++q) {
    int i = part*8 + q;
    p += accv[b*RD + i] * Wf[i*TGT + tg];
  }
  __shared__ float pp[16][17];
  pp[part][tg] = p;
  __syncthreads();
  if (tid < 16) {
    float v = bf[tid];
    #pragma unroll
    for (int q = 0; q < 16; ++q) v += pp[q][tid];
    float mx = v;
    for (int off = 8; off; off >>= 1) mx = fmaxf(mx, __shfl_xor(mx, off, 16));
    float e = __expf(v - mx);
    float s = e;
    for (int off = 8; off; off >>= 1) s += __shfl_xor(s, off, 16);
    out[b*TGT + tid] = e / s;
  }
}

extern "C" void kernel_launch(void* const* d_in, const int* in_sizes, int n_in,
                              void* d_out, int out_size, void* d_ws, size_t ws_size,
                              hipStream_t stream)
{
  const float* g    = (const float*)d_in[0];
  const float* h_in = (const float*)d_in[1];
  const float* e    = (const float*)d_in[2];
  const float* H0   = (const float*)d_in[3];
  const float* H1   = (const float*)d_in[4];
  const float* H2   = (const float*)d_in[5];
  const float* W0   = (const float*)d_in[6];
  const float* W1   = (const float*)d_in[7];
  const float* W2   = (const float*)d_in[8];
  const float* W3   = (const float*)d_in[9];
  const float* Wf   = (const float*)d_in[10];
  const float* bf   = (const float*)d_in[11];
  float* out = (float*)d_out;

  char* base = (char*)d_ws;
  size_t off = 0;
  auto alloc = [&](size_t bytes) -> void* {
    void* p = base + off;
    off = (off + bytes + 255) & ~(size_t)255;
    return p;
  };
  int*   adj_idx   = (int*)  alloc((size_t)ROWS*KMAX*sizeof(int));
  float* adj_val   = (float*)alloc((size_t)ROWS*KMAX*sizeof(float));
  int*   nnzArr    = (int*)  alloc((size_t)ROWS*sizeof(int));
  int*   bucketArr = (int*)  alloc((size_t)ROWS*sizeof(int));
  float* me        = (float*)alloc((size_t)ROWS*EDGE_F*sizeof(float));
  int*   perm      = (int*)  alloc((size_t)4*ROWS*sizeof(int));
  int*   counts    = (int*)  alloc(8*sizeof(int) + (size_t)BATCH*RD*sizeof(float));
  float* accv      = (float*)(counts + 8);
  float* h1        = (float*)alloc((size_t)ROWS*NODE_F*sizeof(float)*3);
  float* h2 = h1 + (size_t)ROWS*NODE_F;
  float* h3 = h2 + (size_t)ROWS*NODE_F;

  // 7 dispatches, no memsets, no device fences. Readout layer l (needs h_l,
  // ready before dispatch l+3) rides the idle CUs of step dispatch l+1;
  // only layer 3 needs its own (256-block) dispatch.
  preprocess_kernel<<<ROWS/4, 256, 0, stream>>>(g, e, adj_idx, adj_val, nnzArr, bucketArr, me,
                                                h1, h2, h3, accv, counts);
  scatter_kernel<<<ROWS/256, 256, 0, stream>>>(bucketArr, counts, perm);
  step_ro_kernel<<<STEP_BLKS + RO_BLKS, 256, 0, stream>>>(
      h_in, h1, H0, perm, counts, nnzArr, adj_idx, adj_val, me, g, h_in, W0, accv);
  step_ro_kernel<<<STEP_BLKS + RO_BLKS, 256, 0, stream>>>(
      h1,   h2, H1, perm, counts, nnzArr, adj_idx, adj_val, me, g, h1,   W1, accv);
  step_ro_kernel<<<STEP_BLKS + RO_BLKS, 256, 0, stream>>>(
      h2,   h3, H2, perm, counts, nnzArr, adj_idx, adj_val, me, g, h2,   W2, accv);
  readout_l3_kernel<<<RO_BLKS, 256, 0, stream>>>(h3, W3, accv);
  final_kernel<<<BATCH, 256, 0, stream>>>(accv, Wf, bf, out);
}